// Round 2
// baseline (4749.643 us; speedup 1.0000x reference)
//
#include <hip/hip_runtime.h>

#define V_NODES 30000
#define DIM 300
#define NE 960000
#define NDOCS 8192
#define DLEN 64
#define CM 7500   // QKV chunk rows (30000 = 4*7500)

// ---------------------------------------------------------------------------
// Tiled fp32 GEMM: C[M,N] = A[M,K] @ B[K,N]
// epilogue: v = acc*rowscale[r] + bias[c] + rowv[r]*colv[c]
// BM=128, BN=64, BK=20, 256 thr, 8x4 micro.  Requires K % 20 == 0.
// ---------------------------------------------------------------------------
#define BM 128
#define BN 64
#define BK 20

__global__ __launch_bounds__(256) void sgemm_kernel(
    const float* __restrict__ A, const float* __restrict__ B, float* __restrict__ C,
    int M, int N, int K, const float* __restrict__ bias, const float* __restrict__ rowscale,
    const float* __restrict__ rowv, const float* __restrict__ colv)
{
    __shared__ float As[BK][BM + 4];
    __shared__ float Bs[BK][BN + 4];
    const int tid = threadIdx.x;
    const int bm = blockIdx.y * BM, bn = blockIdx.x * BN;
    const int tx = tid & 15, ty = tid >> 4;

    float acc[8][4];
#pragma unroll
    for (int i = 0; i < 8; i++)
#pragma unroll
        for (int j = 0; j < 4; j++) acc[i][j] = 0.f;

    const int arow = tid >> 1;         // 0..127
    const int akk0 = (tid & 1) * 10;   // 0 or 10
    const int bnl  = tid & 63;         // 0..63
    const int bkr  = tid >> 6;         // 0..3

    for (int k0 = 0; k0 < K; k0 += BK) {
        // ---- stage A tile (transposed: As[k][m]) ----
        {
            int gr = bm + arow;
            if (gr < M) {
                const float* ap = A + (size_t)gr * K + k0 + akk0;
#pragma unroll
                for (int j = 0; j < 10; j++) As[akk0 + j][arow] = ap[j];
            } else {
#pragma unroll
                for (int j = 0; j < 10; j++) As[akk0 + j][arow] = 0.f;
            }
        }
        // ---- stage B tile ----
        {
            int gn = bn + bnl;
            bool nin = gn < N;
#pragma unroll
            for (int p = 0; p < 5; p++) {
                int kk = p * 4 + bkr;
                Bs[kk][bnl] = nin ? B[(size_t)(k0 + kk) * N + gn] : 0.f;
            }
        }
        __syncthreads();
#pragma unroll
        for (int kk = 0; kk < BK; kk++) {
            float4 a0 = *(const float4*)&As[kk][ty * 8];
            float4 a1 = *(const float4*)&As[kk][ty * 8 + 4];
            float4 b  = *(const float4*)&Bs[kk][tx * 4];
            float av[8] = {a0.x, a0.y, a0.z, a0.w, a1.x, a1.y, a1.z, a1.w};
            float bv[4] = {b.x, b.y, b.z, b.w};
#pragma unroll
            for (int i = 0; i < 8; i++)
#pragma unroll
                for (int j = 0; j < 4; j++)
                    acc[i][j] = fmaf(av[i], bv[j], acc[i][j]);
        }
        __syncthreads();
    }
    // ---- epilogue ----
#pragma unroll
    for (int i = 0; i < 8; i++) {
        int r = bm + ty * 8 + i;
        if (r >= M) continue;
        float rs = rowscale ? rowscale[r] : 1.f;
        float rv = rowv ? rowv[r] : 0.f;
#pragma unroll
        for (int j = 0; j < 4; j++) {
            int c = bn + tx * 4 + j;
            if (c < N) {
                float v = acc[i][j] * rs;
                if (bias) v += bias[c];
                if (rowv) v += rv * colv[c];
                C[(size_t)r * N + c] = v;
            }
        }
    }
}

// ---------------------------------------------------------------------------
// Graph kernels
// ---------------------------------------------------------------------------
__global__ void degree_kernel(const int* __restrict__ src, const int* __restrict__ dst,
                              int* __restrict__ dout, int* __restrict__ din, int n)
{
    int e = blockIdx.x * blockDim.x + threadIdx.x;
    if (e >= n) return;
    atomicAdd(&dout[src[e]], 1);
    atomicAdd(&din[dst[e]], 1);
}

__global__ void nsnd_kernel(const int* __restrict__ dout, const int* __restrict__ din,
                            float* __restrict__ ns, float* __restrict__ nd, int n)
{
    int i = blockIdx.x * blockDim.x + threadIdx.x;
    if (i >= n) return;
    ns[i] = rsqrtf((float)max(dout[i], 1));
    nd[i] = rsqrtf((float)max(din[i], 1));
}

// single-block scan -> exclusive row_ptr (row_ptr[0]=0, row_ptr[n]=total)
__global__ void scan_kernel(const int* __restrict__ deg, int* __restrict__ row_ptr, int n)
{
    __shared__ int sdata[1024];
    __shared__ int carry;
    if (threadIdx.x == 0) { carry = 0; row_ptr[0] = 0; }
    __syncthreads();
    for (int base = 0; base < n; base += 1024) {
        int i = base + (int)threadIdx.x;
        int v = (i < n) ? deg[i] : 0;
        sdata[threadIdx.x] = v;
        __syncthreads();
        for (int off = 1; off < 1024; off <<= 1) {
            int t = (threadIdx.x >= (unsigned)off) ? sdata[threadIdx.x - off] : 0;
            __syncthreads();
            sdata[threadIdx.x] += t;
            __syncthreads();
        }
        if (i < n) row_ptr[i + 1] = carry + sdata[threadIdx.x];
        __syncthreads();
        if (threadIdx.x == 1023) carry += sdata[1023];
        __syncthreads();
    }
}

__global__ void fill_kernel(const int* __restrict__ src, const int* __restrict__ dst,
                            const int* __restrict__ row_ptr, int* __restrict__ cursor,
                            int* __restrict__ col, int n)
{
    int e = blockIdx.x * blockDim.x + threadIdx.x;
    if (e >= n) return;
    int d = dst[e];
    int p = atomicAdd(&cursor[d], 1);
    col[row_ptr[d] + p] = src[e];
}

// out[v,:] = (sum over in-edges of hs[src,:]) * nd[v] + bias (+ residual)
__global__ __launch_bounds__(256) void agg_kernel(
    const float* __restrict__ hs, const int* __restrict__ row_ptr, const int* __restrict__ col,
    const float* __restrict__ ndv, const float* __restrict__ bias,
    const float* __restrict__ residual, float* __restrict__ out)
{
    int v = blockIdx.x;
    int t = threadIdx.x;
    int beg = row_ptr[v], end = row_ptr[v + 1];
    float a0 = 0.f, a1 = 0.f;
    for (int e = beg; e < end; e++) {
        int s = col[e];
        const float* r = hs + (size_t)s * DIM;
        a0 += r[t];
        if (t < DIM - 256) a1 += r[t + 256];
    }
    float nv = ndv[v];
    float* o = out + (size_t)v * DIM;
    float r0 = a0 * nv + bias[t];
    if (residual) r0 += residual[(size_t)v * DIM + t];
    o[t] = r0;
    if (t < DIM - 256) {
        float r1 = a1 * nv + bias[t + 256];
        if (residual) r1 += residual[(size_t)v * DIM + t + 256];
        o[t + 256] = r1;
    }
}

// ---------------------------------------------------------------------------
// 30-head attention over 3 view positions, folded with mean over q-positions.
// Q/K/V buffers: [3][cm][DIM].  Writes om rows [r0, r0+cm).
// ---------------------------------------------------------------------------
__global__ __launch_bounds__(256) void attn_kernel(
    const float* __restrict__ Qb, const float* __restrict__ Kb, const float* __restrict__ Vb,
    float* __restrict__ om, int cm, int r0)
{
    int t = blockIdx.x * 256 + threadIdx.x;
    if (t >= cm * 30) return;
    int i = t / 30, h = t - i * 30;
    int off = h * 10;
    float q[3][10], k[3][10], v[3][10];
#pragma unroll
    for (int s = 0; s < 3; s++) {
        const float* qp = Qb + ((size_t)s * cm + i) * DIM + off;
        const float* kp = Kb + ((size_t)s * cm + i) * DIM + off;
        const float* vp = Vb + ((size_t)s * cm + i) * DIM + off;
#pragma unroll
        for (int d = 0; d < 10; d++) { q[s][d] = qp[d]; k[s][d] = kp[d]; v[s][d] = vp[d]; }
    }
    const float scale = 0.31622776601683794f;  // 1/sqrt(10)
    float w[3] = {0.f, 0.f, 0.f};
#pragma unroll
    for (int qi = 0; qi < 3; qi++) {
        float sc[3];
#pragma unroll
        for (int ki = 0; ki < 3; ki++) {
            float s_ = 0.f;
#pragma unroll
            for (int d = 0; d < 10; d++) s_ = fmaf(q[qi][d], k[ki][d], s_);
            sc[ki] = s_ * scale;
        }
        float m = fmaxf(sc[0], fmaxf(sc[1], sc[2]));
        float e0 = expf(sc[0] - m), e1 = expf(sc[1] - m), e2 = expf(sc[2] - m);
        float inv = 1.f / (e0 + e1 + e2);
        w[0] += e0 * inv; w[1] += e1 * inv; w[2] += e2 * inv;
    }
    float* op = om + (size_t)(r0 + i) * DIM + off;
#pragma unroll
    for (int d = 0; d < 10; d++)
        op[d] = (w[0] * v[0][d] + w[1] * v[1][d] + w[2] * v[2][d]) * (1.f / 3.f);
}

// DM[d,:] = (1/64) * sum over valid tokens of om[idx,:];  DC[d] = cnt/64
__global__ __launch_bounds__(256) void docmean_kernel(
    const float* __restrict__ om, const int* __restrict__ adj,
    float* __restrict__ DM, float* __restrict__ DC)
{
    int d = blockIdx.x;
    int t = threadIdx.x;
    float a0 = 0.f, a1 = 0.f;
    int cnt = 0;
    for (int l = 0; l < DLEN; l++) {
        int idx = adj[d * DLEN + l];
        if (idx < V_NODES) {
            cnt++;
            const float* r = om + (size_t)idx * DIM;
            a0 += r[t];
            if (t < DIM - 256) a1 += r[t + 256];
        }
    }
    DM[(size_t)d * DIM + t] = a0 * (1.f / 64.f);
    if (t < DIM - 256) DM[(size_t)d * DIM + t + 256] = a1 * (1.f / 64.f);
    if (t == 0) DC[d] = (float)cnt * (1.f / 64.f);
}

// ---------------------------------------------------------------------------
extern "C" void kernel_launch(void* const* d_in, const int* in_sizes, int n_in,
                              void* d_out, int out_size, void* d_ws, size_t ws_size,
                              hipStream_t stream)
{
    const int* adj = (const int*)d_in[0];
    const int* srcs[3] = {(const int*)d_in[1], (const int*)d_in[3], (const int*)d_in[5]};
    const int* dsts[3] = {(const int*)d_in[2], (const int*)d_in[4], (const int*)d_in[6]};
    const float* emb = (const float*)d_in[8];
    const float* W1[3] = {(const float*)d_in[9],  (const float*)d_in[13], (const float*)d_in[17]};
    const float* b1[3] = {(const float*)d_in[10], (const float*)d_in[14], (const float*)d_in[18]};
    const float* W2[3] = {(const float*)d_in[11], (const float*)d_in[15], (const float*)d_in[19]};
    const float* b2[3] = {(const float*)d_in[12], (const float*)d_in[16], (const float*)d_in[20]};
    const float* Wq = (const float*)d_in[21], *bq = (const float*)d_in[22];
    const float* Wk = (const float*)d_in[23], *bk = (const float*)d_in[24];
    const float* Wv = (const float*)d_in[25], *bv = (const float*)d_in[26];
    const float* Wo = (const float*)d_in[27], *bo = (const float*)d_in[28];
    const float* Wd = (const float*)d_in[29], *bd = (const float*)d_in[30];
    const float* Wfc = (const float*)d_in[31], *bfc = (const float*)d_in[32];
    float* out = (float*)d_out;

    // ---- workspace carve ----
    char* p = (char*)d_ws;
    auto alloc = [&](size_t bytes) { void* r = (void*)p; p += (bytes + 255) & ~(size_t)255; return r; };
    float* ns  = (float*)alloc(V_NODES * 4);
    float* nd  = (float*)alloc(V_NODES * 4);
    int* ibase = (int*)alloc(3 * V_NODES * 4);   // deg_out | deg_in | cursor
    int* deg0 = ibase, *deg1 = ibase + V_NODES, *cursor = ibase + 2 * V_NODES;
    int* row_ptr = (int*)alloc((V_NODES + 1) * 4);
    int* col     = (int*)alloc(NE * 4);
    float* Wdf   = (float*)alloc(300 * 20 * 4);
    float* Wcomb = (float*)alloc(300 * 20 * 4);
    float* v1    = (float*)alloc(20 * 4);
    float* v2    = (float*)alloc(20 * 4);
    float* T1 = (float*)alloc((size_t)V_NODES * DIM * 4);
    float* T2 = (float*)alloc((size_t)V_NODES * DIM * 4);
    float* Bv[3];
    for (int i = 0; i < 3; i++) Bv[i] = (float*)alloc((size_t)V_NODES * DIM * 4);
    float* Kb = (float*)alloc((size_t)3 * CM * DIM * 4);
    float* Vb = (float*)alloc((size_t)3 * CM * DIM * 4);
    float* Qb = T2;                 // T2 free during MHA phase
    float* DM = Bv[0];              // [NDOCS, DIM]  (Bv free after MHA)
    float* DC = Bv[1];              // [NDOCS]

    auto gemm = [&](const float* A, const float* B, float* C, int M, int N, int K,
                    const float* bias, const float* rowscale,
                    const float* rowv = nullptr, const float* colv = nullptr) {
        dim3 grid((N + BN - 1) / BN, (M + BM - 1) / BM);
        hipLaunchKernelGGL(sgemm_kernel, grid, dim3(256), 0, stream,
                           A, B, C, M, N, K, bias, rowscale, rowv, colv);
    };

    const int EB = (NE + 255) / 256;
    const int VB = (V_NODES + 255) / 256;

    // ---- precompute folded tail matrices (tiny GEMMs) ----
    gemm(Wd, Wfc, Wdf, DIM, 20, DIM, nullptr, nullptr);        // Wdf = Wd@Wfc   [300,20]
    gemm(Wo, Wdf, Wcomb, DIM, 20, DIM, nullptr, nullptr);      // Wcomb = Wo@Wdf [300,20]
    gemm(bo, Wdf, v1, 1, 20, DIM, nullptr, nullptr);           // v1 = bo@Wdf    [20]
    gemm(bd, Wfc, v2, 1, 20, DIM, bfc, nullptr);               // v2 = bd@Wfc+bfc[20]

    // ---- three GCN branches ----
    for (int br = 0; br < 3; br++) {
        hipMemsetAsync(ibase, 0, (size_t)3 * V_NODES * 4, stream);
        hipLaunchKernelGGL(degree_kernel, dim3(EB), dim3(256), 0, stream, srcs[br], dsts[br], deg0, deg1, NE);
        hipLaunchKernelGGL(nsnd_kernel, dim3(VB), dim3(256), 0, stream, deg0, deg1, ns, nd, V_NODES);
        hipLaunchKernelGGL(scan_kernel, dim3(1), dim3(1024), 0, stream, deg1, row_ptr, V_NODES);
        hipLaunchKernelGGL(fill_kernel, dim3(EB), dim3(256), 0, stream, srcs[br], dsts[br], row_ptr, cursor, col, NE);
        // layer 1:  T2 = agg(emb@W1 * ns) * nd + b1
        gemm(emb, W1[br], T1, V_NODES, DIM, DIM, nullptr, ns);
        hipLaunchKernelGGL(agg_kernel, dim3(V_NODES), dim3(256), 0, stream, T1, row_ptr, col, nd, b1[br], (const float*)nullptr, T2);
        // layer 2 (+ residual emb):  Bv = agg(T2@W2 * ns) * nd + b2 + emb
        gemm(T2, W2[br], T1, V_NODES, DIM, DIM, nullptr, ns);
        hipLaunchKernelGGL(agg_kernel, dim3(V_NODES), dim3(256), 0, stream, T1, row_ptr, col, nd, b2[br], emb, Bv[br]);
    }

    // ---- MHA pool over the 3 views (chunked), mean-pooled output -> T1 ----
    for (int c = 0; c < V_NODES / CM; c++) {
        int r0 = c * CM;
        for (int s = 0; s < 3; s++) {
            const float* x = Bv[s] + (size_t)r0 * DIM;
            gemm(x, Wq, Qb + (size_t)s * CM * DIM, CM, DIM, DIM, bq, nullptr);
            gemm(x, Wk, Kb + (size_t)s * CM * DIM, CM, DIM, DIM, bk, nullptr);
            gemm(x, Wv, Vb + (size_t)s * CM * DIM, CM, DIM, DIM, bv, nullptr);
        }
        hipLaunchKernelGGL(attn_kernel, dim3((CM * 30 + 255) / 256), dim3(256), 0, stream, Qb, Kb, Vb, T1, CM, r0);
    }

    // ---- doc pipeline (fully folded tail) ----
    hipLaunchKernelGGL(docmean_kernel, dim3(NDOCS), dim3(256), 0, stream, T1, adj, DM, DC);
    // out = DM @ Wcomb + DC*v1 + v2
    gemm(DM, Wcomb, out, NDOCS, 20, DIM, v2, nullptr, DC, v1);
}